// Round 11
// baseline (36.575 us; speedup 1.0000x reference)
//
#include <hip/hip_runtime.h>

#define FS    5
#define NTAP  25
#define Cc    32
#define CG    8                     // channels per block (apply)
#define Hc    128
#define Wc    128
#define HW    (Hc * Wc)

#define TH      8
#define TW      64
#define HALO_H  12                   // TH + 4
#define HALO_W  72                   // [w0-4, w0+68): float4-aligned left edge
#define PLANE   (HALO_H * HALO_W)    // 864 floats
#define F4_PER_PLANE (PLANE / 4)     // 216
#define F4_TOTAL     (CG * F4_PER_PLANE)  // 1728
#define LDS_BYTES    (CG * PLANE * 4)     // 27648 B -> 4-5 blocks/CU

// zero-initialized device global: OOB lanes' DMA source (16B aligned)
__device__ __attribute__((aligned(16))) float ZERO4[4];

__device__ __forceinline__ void gload_lds16(const float* g, float* lds) {
    __builtin_amdgcn_global_load_lds(
        (const __attribute__((address_space(1))) void*)g,
        (__attribute__((address_space(3))) void*)lds, 16, 0, 0);
}

// ================= Kernel 1: pure filter generation =================
// 1 px/thread; xv[32] issued up front (32-deep VMEM pipeline); t-outer so
// each tap-row reads wg[t][0..31] CONSECUTIVE -> s_load_dwordx16 x2 (one
// K$ line per row) instead of 800 stride-128B scalar loads. No LDS.
__global__ __launch_bounds__(256) void gen_kernel(
    const float* __restrict__ x, const float* __restrict__ wg,
    const float* __restrict__ bg, float* __restrict__ filt)
{
    const int p = blockIdx.x * 256 + threadIdx.x;   // pixel in image
    const int b = blockIdx.y;

    const float* xb = x + (size_t)b * Cc * HW + p;
    float xv[Cc];
#pragma unroll
    for (int c = 0; c < Cc; ++c) xv[c] = xb[(size_t)c * HW];

    float f[NTAP];
#pragma unroll
    for (int t = 0; t < NTAP; ++t) f[t] = bg[t];

#pragma unroll
    for (int t = 0; t < NTAP; ++t) {
        const float* wr = wg + t * Cc;              // 32 consecutive floats
#pragma unroll
        for (int c = 0; c < Cc; ++c)
            f[t] = fmaf(wr[c], xv[c], f[t]);
    }

    float* fb = filt + (size_t)b * NTAP * HW + p;
#pragma unroll
    for (int t = 0; t < NTAP; ++t) fb[(size_t)t * HW] = f[t];
}

// ================= Kernel 2: stage + apply (R7 minus gen) =================
// One block = one 8x64 tile, ONE 8-channel group. DMA-stage own 8 halo
// planes; 25 float2 filter loads (filt is L3-resident; 4 sibling ch-group
// blocks share the same 51KB filt slice on one XCD's L2) issued in the DMA
// shadow; single vmcnt(0)+barrier; 5x5 apply, 2 px/thread.
__global__ __launch_bounds__(256, 4) void apply_kernel(
    const float* __restrict__ x, const float* __restrict__ filt,
    float* __restrict__ out)
{
    extern __shared__ float xs[];     // [CG][HALO_H][HALO_W]

    const int tid = threadIdx.x;
    const int bid = blockIdx.x;
    // id = ht + 16*wt + 32*chg + 128*b ; delta(chg)=32 == 0 mod 8 -> the 4
    // ch-group blocks of one tile land on the same XCD (filt L2 locality).
    const int ht  = bid & 15;
    const int wt  = (bid >> 4) & 1;
    const int chg = (bid >> 5) & 3;
    const int b   = bid >> 7;
    const int h0  = ht * TH;
    const int w0  = wt * TW;
    const int c0  = chg * CG;

    const float* xo = x + ((size_t)b * Cc + c0) * HW;

    // ---- DMA-stage own 8 halo planes (<=7 dwordx4 per thread) ----
#pragma unroll
    for (int k = 0; k < 7; ++k) {
        const int f = k * 256 + tid;
        if (f < F4_TOTAL) {                      // k==6: wave-uniform guard
            const int c  = f / F4_PER_PLANE;     // /216 (magic mul)
            const int rm = f - c * F4_PER_PLANE;
            const int r  = rm / 18;
            const int c4 = rm - r * 18;
            const int gh = h0 - 2 + r;
            const int gw = w0 - 4 + 4 * c4;
            const bool v = ((unsigned)gh < (unsigned)Hc) &&
                           ((unsigned)gw <= (unsigned)(Wc - 4));
            const float* src = v ? (xo + (size_t)c * HW + gh * Wc + gw) : ZERO4;
            gload_lds16(src, xs + (size_t)k * 1024 + (size_t)(tid >> 6) * 256);
        }
    }

    // ---- filter loads in the DMA shadow (2 px per thread) ----
    const int ty = tid >> 5;          // 0..7
    const int tx = tid & 31;          // 0..31
    const int w2 = tx * 2;
    const int centerOff = (h0 + ty) * Wc + (w0 + w2);

    float2 ft[NTAP];
    const float* fb = filt + (size_t)b * NTAP * HW + centerOff;
#pragma unroll
    for (int t = 0; t < NTAP; ++t)
        ft[t] = *reinterpret_cast<const float2*>(fb + (size_t)t * HW);

    // DMA + filter loads complete
    asm volatile("s_waitcnt vmcnt(0)" ::: "memory");
    __builtin_amdgcn_sched_barrier(0);
    __builtin_amdgcn_s_barrier();

    // ---- apply: 5x5 over own 8 channels ----
    float* ob = out + ((size_t)b * Cc + c0) * HW + centerOff;
#pragma unroll
    for (int c = 0; c < CG; ++c) {
        const float* p = xs + c * PLANE + ty * HALO_W + (w2 + 2);
        float ax = 0.f, ay = 0.f;
#pragma unroll
        for (int di = 0; di < FS; ++di) {
            const float* row = p + di * HALO_W;
            const float2 s01 = *reinterpret_cast<const float2*>(row);
            const float2 s23 = *reinterpret_cast<const float2*>(row + 2);
            const float2 s45 = *reinterpret_cast<const float2*>(row + 4);
            const float s0 = s01.x, s1 = s01.y, s2 = s23.x,
                        s3 = s23.y, s4 = s45.x, s5 = s45.y;
            ax = fmaf(ft[di * FS + 0].x, s0, ax);  ay = fmaf(ft[di * FS + 0].y, s1, ay);
            ax = fmaf(ft[di * FS + 1].x, s1, ax);  ay = fmaf(ft[di * FS + 1].y, s2, ay);
            ax = fmaf(ft[di * FS + 2].x, s2, ax);  ay = fmaf(ft[di * FS + 2].y, s3, ay);
            ax = fmaf(ft[di * FS + 3].x, s3, ax);  ay = fmaf(ft[di * FS + 3].y, s4, ay);
            ax = fmaf(ft[di * FS + 4].x, s4, ax);  ay = fmaf(ft[di * FS + 4].y, s5, ay);
        }
        *reinterpret_cast<float2*>(ob + (size_t)c * HW) = make_float2(ax, ay);
    }
}

extern "C" void kernel_launch(void* const* d_in, const int* in_sizes, int n_in,
                              void* d_out, int out_size, void* d_ws, size_t ws_size,
                              hipStream_t stream) {
    const float* x  = (const float*)d_in[0];
    const float* wg = (const float*)d_in[1];
    const float* bg = (const float*)d_in[2];
    float* out = (float*)d_out;
    float* filt = (float*)d_ws;       // 8*25*16384*4 = 13.1 MB

    gen_kernel<<<dim3(HW / 256, 8), 256, 0, stream>>>(x, wg, bg, filt);
    apply_kernel<<<dim3(1024), 256, LDS_BYTES, stream>>>(x, filt, out);
}